// Round 3
// 26614.783 us; speedup vs baseline: 2.7589x; 2.7589x over previous
//
#include <hip/hip_runtime.h>
#include <math.h>

// Problem constants
#define SEQ 2048
#define NBATCH 64
#define IN_DIM 512
#define HD 512
#define NG 1024                 // 2*H gate width
#define BH (NBATCH * HD)        // 32768 elements per timestep of h
#define NWG 8                   // workgroups in recurrent kernel

typedef __attribute__((ext_vector_type(8))) short short8;
typedef __attribute__((ext_vector_type(4))) float float4v;
typedef __attribute__((ext_vector_type(2))) unsigned long long ull2v;

__device__ __forceinline__ unsigned short f2bf(float f) {
    unsigned u = __builtin_bit_cast(unsigned, f);
    u += 0x7fffu + ((u >> 16) & 1u);            // RNE
    return (unsigned short)(u >> 16);
}
__device__ __forceinline__ float bf2f(unsigned short s) {
    unsigned u = ((unsigned)s) << 16;
    return __builtin_bit_cast(float, u);
}

// ---------------------------------------------------------------------------
// Kernel 1: x-projection GEMM (unchanged).
// XGT[t][gatecol][b] (bf16, transposed!) = x@Wg_x + bg      (cols 0..1023)
// out[t][b][c]       (fp32, row-major)   = x@Wc_x + bc      (XC; overwritten by h_t later)
// ---------------------------------------------------------------------------
__global__ __launch_bounds__(256) void xproj_kernel(
    const float* __restrict__ x, const float* __restrict__ Wg,
    const float* __restrict__ bg, const float* __restrict__ Wc,
    const float* __restrict__ bc, unsigned short* __restrict__ XGT,
    float* __restrict__ out)
{
    __shared__ unsigned short Bs[128 * 40];
    const int tid  = threadIdx.x;
    const int lane = tid & 63;
    const int q = lane >> 4, ln = lane & 15;
    const int wid = tid >> 6;
    const int wr = wid & 1, wcq = wid >> 1;     // 2x2 wave grid, 64x64 each
    const int m0 = blockIdx.y * 128;
    const int nb = blockIdx.x;                  // 0..11 ; <8 => Wg half, else Wc half
    const bool isG = (nb < 8);
    const float* Wbase = isG ? (Wg + nb * 128) : (Wc + (nb - 8) * 128);
    const int   ldw   = isG ? NG : HD;
    const float* bias = isG ? (bg + nb * 128) : (bc + (nb - 8) * 128);
    const int sc = tid & 127, kh = tid >> 7;    // staging: col, k-half

    float4v acc[4][4];
    for (int i = 0; i < 4; ++i)
        for (int j = 0; j < 4; ++j) acc[i][j] = (float4v){0.f, 0.f, 0.f, 0.f};

    for (int kk = 0; kk < IN_DIM; kk += 32) {
        unsigned short us[16];
        for (int i = 0; i < 16; ++i)
            us[i] = f2bf(Wbase[(size_t)(kk + kh * 16 + i) * ldw + sc]);
        short8 p0, p1;
        for (int i = 0; i < 8; ++i) {
            ((unsigned short*)&p0)[i] = us[i];
            ((unsigned short*)&p1)[i] = us[i + 8];
        }
        short8* dst = (short8*)(&Bs[sc * 40 + kh * 16]);
        dst[0] = p0; dst[1] = p1;
        __syncthreads();

        short8 af[4], bfr[4];
        for (int mi = 0; mi < 4; ++mi) {
            const float* ap = x + (size_t)(m0 + wr * 64 + mi * 16 + ln) * IN_DIM + kk + q * 8;
            float4v f0 = *(const float4v*)ap;
            float4v f1 = *(const float4v*)(ap + 4);
            short8 a;
            for (int j = 0; j < 4; ++j) {
                ((unsigned short*)&a)[j]     = f2bf(f0[j]);
                ((unsigned short*)&a)[4 + j] = f2bf(f1[j]);
            }
            af[mi] = a;
        }
        for (int ni = 0; ni < 4; ++ni)
            bfr[ni] = *(const short8*)(&Bs[(wcq * 64 + ni * 16 + ln) * 40 + q * 8]);

        for (int mi = 0; mi < 4; ++mi)
            for (int ni = 0; ni < 4; ++ni)
                acc[mi][ni] = __builtin_amdgcn_mfma_f32_16x16x32_bf16(
                    af[mi], bfr[ni], acc[mi][ni], 0, 0, 0);
        __syncthreads();
    }

    for (int ni = 0; ni < 4; ++ni) {
        int cb = wcq * 64 + ni * 16 + ln;
        int col = nb * 128 + cb;
        float bv = bias[cb];
        for (int mi = 0; mi < 4; ++mi) {
            int mrow0 = m0 + wr * 64 + mi * 16 + q * 4;   // 4 consecutive rows, same t
            if (isG) {
                int tt = mrow0 >> 6, b0 = mrow0 & 63;
                unsigned long long pk = 0;
                for (int rg = 0; rg < 4; ++rg)
                    pk |= (unsigned long long)f2bf(acc[mi][ni][rg] + bv) << (16 * rg);
                *(unsigned long long*)(XGT + ((size_t)tt * NG + col) * 64 + b0) = pk;
            } else {
                for (int rg = 0; rg < 4; ++rg)
                    out[(size_t)(mrow0 + rg) * HD + (nb - 8) * 128 + cb] = acc[mi][ni][rg] + bv;
            }
        }
    }
}

// ---------------------------------------------------------------------------
// Kernel 2: persistent recurrent kernel, 8 wgs x 256 threads.
// Sync protocol identical to previous version (relaxed agent atomics + flags).
// NEW: cross-wg exchange matrices (hbf/rhb, 64 KiB bf16 each) are bulk-staged
// cooperatively into a single XOR-swizzled LDS tile per phase (one exposed LLC
// latency instead of ~8 per phase, no 4x per-wave duplication), and MFMA
// A-fragments are read from LDS. fp32 out stores deferred past flag release.
// ---------------------------------------------------------------------------
__device__ __forceinline__ void poll8(const int* f) {
    const int lane = threadIdx.x & 63;
    const int* p = f + (lane & 7);
    for (;;) {
        int v = __hip_atomic_load(p, __ATOMIC_RELAXED, __HIP_MEMORY_SCOPE_AGENT);
        if (__all(v != 0)) break;
        __builtin_amdgcn_s_sleep(1);
    }
    __atomic_signal_fence(__ATOMIC_SEQ_CST);   // compiler-only: no hoisting
}

// swizzled LDS byte offset for logical (row, byte-col) in a [64][1024B] tile
__device__ __forceinline__ int swzoff(int row, int colb) {
    return row * 1024 + (colb ^ ((row & 7) << 4));
}

__global__ __launch_bounds__(256, 1) void gru_rec_kernel(
    const unsigned short* __restrict__ XGT, const float* __restrict__ h0,
    const float* __restrict__ Wg, const float* __restrict__ Wc,
    float* __restrict__ out, unsigned short* __restrict__ hbf,
    unsigned short* __restrict__ rhb, int* flags_rh, int* flags_h)
{
    __shared__ __align__(16) unsigned short Hs[64 * 512]; // 64 KiB swizzled staging (h, then rh)
    __shared__ float hloc[64][68];            // h_{t-1} fp32, wg's 64-col slice
    __shared__ float zloc[64][68];            // z_t fp32
    __shared__ unsigned short xb16[64][68];   // bf16 staging (rh, then h)

    const int g   = blockIdx.x;
    const int tid = threadIdx.x;
    const int w = tid >> 6, lane = tid & 63;
    const int q = lane >> 4, n = lane & 15;
    const bool isR = (w >= 2);
    const int gbase = (isR ? 512 : 0) + g * 64 + (w & 1) * 32;  // phase A gate col base
    const int lbase = (w & 1) * 32;                              // local col base
    const int cb    = g * 64 + w * 16 + n;                       // cand col (phase B)

    // ---- persistent weights (one-time) ----
    short8 WA[2][16], WB[16];
#pragma unroll
    for (int nt = 0; nt < 2; ++nt)
#pragma unroll
        for (int ks = 0; ks < 16; ++ks) {
            short8 a;
            for (int j = 0; j < 8; ++j)
                ((unsigned short*)&a)[j] =
                    f2bf(Wg[(size_t)(IN_DIM + ks * 32 + q * 8 + j) * NG + gbase + nt * 16 + n]);
            WA[nt][ks] = a;
        }
#pragma unroll
    for (int ks = 0; ks < 16; ++ks) {
        short8 a;
        for (int j = 0; j < 8; ++j)
            ((unsigned short*)&a)[j] =
                f2bf(Wc[(size_t)(IN_DIM + ks * 32 + q * 8 + j) * HD + cb]);
        WB[ks] = a;
    }

    for (int k = 0; k < 16; ++k) {            // hloc <- h0 slice
        int idx = tid + k * 256; int b = idx >> 6, c = idx & 63;
        hloc[b][c] = h0[b * HD + g * 64 + c];
    }
    __syncthreads();

    for (int t = 0; t < SEQ; ++t) {
        if (t > 0) poll8(flags_h + (size_t)(t - 1) * NWG);

        // ---- bulk-stage h_{t-1} (full 64x512 bf16) : 32 coalesced 8B agent
        //      loads per thread, all in flight at once ----
        unsigned long long sv0[16], sv1[16];
#pragma unroll
        for (int i = 0; i < 16; ++i) {
            const unsigned long long* p =
                (const unsigned long long*)(hbf + (size_t)(i * 256 + tid) * 8);
            sv0[i] = __hip_atomic_load(p,     __ATOMIC_RELAXED, __HIP_MEMORY_SCOPE_AGENT);
            sv1[i] = __hip_atomic_load(p + 1, __ATOMIC_RELAXED, __HIP_MEMORY_SCOPE_AGENT);
        }
        // prefetch x-projections (overlap staging drain + phase A)
        unsigned long long xgv[4][2];
#pragma unroll
        for (int mi = 0; mi < 4; ++mi)
#pragma unroll
            for (int nt = 0; nt < 2; ++nt)
                xgv[mi][nt] = *(const unsigned long long*)
                    (XGT + ((size_t)t * NG + gbase + nt * 16 + n) * 64 + mi * 16 + q * 4);
        float xc[4][4];
#pragma unroll
        for (int mi = 0; mi < 4; ++mi)
#pragma unroll
            for (int rg = 0; rg < 4; ++rg)
                xc[mi][rg] = out[(size_t)t * BH + (mi * 16 + q * 4 + rg) * HD + cb];

#pragma unroll
        for (int i = 0; i < 16; ++i) {
            int g16 = i * 256 + tid;          // 16B granule index
            int row = g16 >> 6;               // 64 granules per 1024B row
            int colb = (g16 & 63) << 4;
            ull2v v; v.x = sv0[i]; v.y = sv1[i];
            *(ull2v*)((char*)Hs + swzoff(row, colb)) = v;
        }
        __syncthreads();

        // ---- phase A: gates = h_{t-1} @ Wg_h + XG (A-fragments from LDS) ----
        float4v accA[4][2];
#pragma unroll
        for (int mi = 0; mi < 4; ++mi)
#pragma unroll
            for (int nt = 0; nt < 2; ++nt) accA[mi][nt] = (float4v){0.f, 0.f, 0.f, 0.f};

#pragma unroll
        for (int kb = 0; kb < 16; ++kb) {     // 16 k-blocks of 32
            short8 af[4];
            int colb = kb * 64 + q * 16;
#pragma unroll
            for (int mi = 0; mi < 4; ++mi) {
                int row = mi * 16 + n;
                af[mi] = *(const short8*)((const char*)Hs + swzoff(row, colb));
            }
#pragma unroll
            for (int mi = 0; mi < 4; ++mi)
#pragma unroll
                for (int nt = 0; nt < 2; ++nt)
                    accA[mi][nt] = __builtin_amdgcn_mfma_f32_16x16x32_bf16(
                        af[mi], WA[nt][kb], accA[mi][nt], 0, 0, 0);
        }

        // epilogue A: sigmoid; z -> zloc, rh -> xb16
#pragma unroll
        for (int mi = 0; mi < 4; ++mi)
#pragma unroll
            for (int nt = 0; nt < 2; ++nt) {
                unsigned long long xu = xgv[mi][nt];
#pragma unroll
                for (int rg = 0; rg < 4; ++rg) {
                    float gs = accA[mi][nt][rg] + bf2f((unsigned short)(xu >> (16 * rg)));
                    float s = 1.f / (1.f + __expf(-gs));
                    int b = mi * 16 + q * 4 + rg, lc = lbase + nt * 16 + n;
                    if (!isR) zloc[b][lc] = s;
                    else      xb16[b][lc] = f2bf(s * hloc[b][lc]);
                }
            }
        __syncthreads();
        // export rh (packed 8B agent stores)
#pragma unroll
        for (int i = 0; i < 4; ++i) {
            int j = tid + i * 256; int b = j >> 4, c4 = j & 15;
            unsigned long long v = *(const unsigned long long*)(&xb16[b][c4 * 4]);
            __hip_atomic_store((unsigned long long*)(rhb + b * HD + g * 64 + c4 * 4), v,
                               __ATOMIC_RELAXED, __HIP_MEMORY_SCOPE_AGENT);
        }
        __syncthreads();   // waitcnt(0) before barrier drains all waves' stores
        if (tid == 0)
            __hip_atomic_store(flags_rh + (size_t)t * NWG + g, 1,
                               __ATOMIC_RELAXED, __HIP_MEMORY_SCOPE_AGENT);

        poll8(flags_rh + (size_t)t * NWG);

        // ---- bulk-stage rh (full 64x512 bf16) into same LDS tile ----
        // (safe: export-rh __syncthreads guarantees all waves are past
        //  phase-A Hs reads before any wave overwrites Hs)
#pragma unroll
        for (int i = 0; i < 16; ++i) {
            const unsigned long long* p =
                (const unsigned long long*)(rhb + (size_t)(i * 256 + tid) * 8);
            sv0[i] = __hip_atomic_load(p,     __ATOMIC_RELAXED, __HIP_MEMORY_SCOPE_AGENT);
            sv1[i] = __hip_atomic_load(p + 1, __ATOMIC_RELAXED, __HIP_MEMORY_SCOPE_AGENT);
        }
#pragma unroll
        for (int i = 0; i < 16; ++i) {
            int g16 = i * 256 + tid;
            int row = g16 >> 6;
            int colb = (g16 & 63) << 4;
            ull2v v; v.x = sv0[i]; v.y = sv1[i];
            *(ull2v*)((char*)Hs + swzoff(row, colb)) = v;
        }
        __syncthreads();

        // ---- phase B: cand = tanh(rh @ Wc_h + XC); h = (1-z)h + z*cand ----
        float4v accB[4];
#pragma unroll
        for (int mi = 0; mi < 4; ++mi) accB[mi] = (float4v){0.f, 0.f, 0.f, 0.f};
#pragma unroll
        for (int kb = 0; kb < 16; ++kb) {
            short8 af[4];
            int colb = kb * 64 + q * 16;
#pragma unroll
            for (int mi = 0; mi < 4; ++mi) {
                int row = mi * 16 + n;
                af[mi] = *(const short8*)((const char*)Hs + swzoff(row, colb));
            }
#pragma unroll
            for (int mi = 0; mi < 4; ++mi)
                accB[mi] = __builtin_amdgcn_mfma_f32_16x16x32_bf16(
                    af[mi], WB[kb], accB[mi], 0, 0, 0);
        }

        float hnr[4][4];
#pragma unroll
        for (int mi = 0; mi < 4; ++mi)
#pragma unroll
            for (int rg = 0; rg < 4; ++rg) {
                int b = mi * 16 + q * 4 + rg, lc = w * 16 + n;
                float cpre = accB[mi][rg] + xc[mi][rg];
                float e  = __expf(2.f * cpre);
                float cd = 1.f - 2.f / (e + 1.f);      // tanh
                float z  = zloc[b][lc];
                float hp = hloc[b][lc];
                float hn = (1.f - z) * hp + z * cd;
                hloc[b][lc] = hn;
                xb16[b][lc] = f2bf(hn);
                hnr[mi][rg] = hn;
            }
        __syncthreads();
        // export h bf16
#pragma unroll
        for (int i = 0; i < 4; ++i) {
            int j = tid + i * 256; int b = j >> 4, c4 = j & 15;
            unsigned long long v = *(const unsigned long long*)(&xb16[b][c4 * 4]);
            __hip_atomic_store((unsigned long long*)(hbf + b * HD + g * 64 + c4 * 4), v,
                               __ATOMIC_RELAXED, __HIP_MEMORY_SCOPE_AGENT);
        }
        __syncthreads();
        if (tid == 0)
            __hip_atomic_store(flags_h + (size_t)t * NWG + g, 1,
                               __ATOMIC_RELAXED, __HIP_MEMORY_SCOPE_AGENT);

        // deferred fp32 out stores (no cross-wg consumer; drain overlaps
        // next step's poll instead of sitting inside the pre-flag barrier)
#pragma unroll
        for (int mi = 0; mi < 4; ++mi)
#pragma unroll
            for (int rg = 0; rg < 4; ++rg) {
                int b = mi * 16 + q * 4 + rg;
                out[(size_t)t * BH + b * HD + cb] = hnr[mi][rg];
            }
        if (t == SEQ - 1) {
#pragma unroll
            for (int mi = 0; mi < 4; ++mi)
#pragma unroll
                for (int rg = 0; rg < 4; ++rg) {
                    int b = mi * 16 + q * 4 + rg;
                    out[(size_t)SEQ * BH + b * HD + cb] = hnr[mi][rg];
                }
        }
    }
}

__global__ __launch_bounds__(256) void init_h_kernel(
    const float* __restrict__ h0, unsigned short* __restrict__ hbf)
{
    int i = blockIdx.x * 256 + threadIdx.x;
    if (i < BH) hbf[i] = f2bf(h0[i]);
}

// ---------------------------------------------------------------------------
extern "C" void kernel_launch(void* const* d_in, const int* in_sizes, int n_in,
                              void* d_out, int out_size, void* d_ws, size_t ws_size,
                              hipStream_t stream)
{
    const float* x  = (const float*)d_in[0];
    const float* h0 = (const float*)d_in[1];
    const float* Wg = (const float*)d_in[2];
    const float* bg = (const float*)d_in[3];
    const float* Wc = (const float*)d_in[4];
    const float* bc = (const float*)d_in[5];
    float* out = (float*)d_out;
    char*  ws  = (char*)d_ws;

    const size_t XG_BYTES = (size_t)SEQ * NBATCH * NG * 2;   // 256 MiB bf16 (transposed)
    unsigned short* XGT = (unsigned short*)(ws);
    unsigned short* rhb = (unsigned short*)(ws + XG_BYTES);               // 64 KiB
    unsigned short* hbf = (unsigned short*)(ws + XG_BYTES + 65536);       // 64 KiB
    int* flags = (int*)(ws + XG_BYTES + 131072);
    const size_t FLAG_BYTES = (size_t)2 * SEQ * NWG * sizeof(int);        // 128 KiB
    if (ws_size < XG_BYTES + 131072 + FLAG_BYTES) return;

    hipMemsetAsync(flags, 0, FLAG_BYTES, stream);
    init_h_kernel<<<dim3(BH / 256), dim3(256), 0, stream>>>(h0, hbf);
    xproj_kernel<<<dim3(12, 1024), dim3(256), 0, stream>>>(x, Wg, bg, Wc, bc, XGT, out);
    gru_rec_kernel<<<dim3(NWG), dim3(256), 0, stream>>>(XGT, h0, Wg, Wc, out, hbf,
                                                        rhb, flags, flags + (size_t)SEQ * NWG);
}